// Round 3
// baseline (789.603 us; speedup 1.0000x reference)
//
#include <hip/hip_runtime.h>
#include <hip/hip_bf16.h>

// LCA sparsifier: 10 iterations of v = 0.9v + 0.1u - 0.1*(a@G); a = soft(v, lam)
// R3 changes vs R2 (theory: LDS A-read was the longest pipe at 12.3k cyc/unit-iter):
//  - 64x64 wave tiles (acc[2][2]) -> each A-fragment feeds 2 B-cols: LDS A-read
//    traffic HALVED. Block = 128 rows x 512 cols, 16 waves (wr in {0,1}, wc in 0..7).
//  - uu evicted from registers (64x64 acc needs all 64 acc regs; acc+uu = 176 regs
//    would drop to 8 waves/CU = R0's failure). u reloaded from global (L3-resident)
//    in each epilogue via nontemporal loads -> numerics EXACT, 16 waves/CU kept.
//  - single-buffered sA[128][520] = 133 KB (same LDS as R2), 2 barriers/iter.
//  - final stores + u reloads nontemporal: keep L2 free for G.

typedef __attribute__((ext_vector_type(8))) short bf16x8;
typedef __attribute__((ext_vector_type(16))) float f32x16;

#define ETA 0.1f

__device__ __forceinline__ unsigned short f2bf(float f) {
  union { float f; unsigned u; } x; x.f = f;
  unsigned r = x.u + 0x7fffu + ((x.u >> 16) & 1u);  // round-to-nearest-even
  return (unsigned short)(r >> 16);
}

// ---- prep: G = 0.5(Graw + Graw^T), zero diag, bf16, swizzled into
// mfma_f32_32x32x16_bf16 B-fragment order: B[k][n], lane = (n&31) + 32*((k>>3)&1),
// j = k&7, frag index = (kk*16 + ct)*64 + lane  with kk=k>>4, ct=n>>5.
__global__ void prep_G(const float* __restrict__ Graw, unsigned short* __restrict__ Gb) {
  int idx = blockIdx.x * blockDim.x + threadIdx.x;  // 512*512 elements
  int k = idx >> 9, n = idx & 511;
  float g = 0.5f * (Graw[k * 512 + n] + Graw[n * 512 + k]);
  if (k == n) g = 0.f;
  int kk = k >> 4, ct = n >> 5;
  int lane = (n & 31) + (((k >> 3) & 1) << 5);
  int j = k & 7;
  Gb[((((kk * 16 + ct) * 64) + lane) << 3) + j] = f2bf(g);
}

__global__ __launch_bounds__(1024, 4) void lca_kernel(
    const float* __restrict__ u_g, const unsigned short* __restrict__ Gb,
    const float* __restrict__ log_lam, float* __restrict__ out) {
  // a-buffer: 128 rows x 512 cols bf16, row stride 520 (1040B = 16*65 -> the
  // 8-lane b128 phases of an A-fragment read cover all 8 bank groups; 0 conflicts).
  __shared__ unsigned short sA[128 * 520];

  const int tid = threadIdx.x;
  const int lane = tid & 63;
  const int wave = tid >> 6;           // 0..15
  const int wr = wave >> 3;            // 0..1: row group (64 rows)
  const int wc = wave & 7;             // 0..7: col group (64 cols)
  const int R0 = blockIdx.x * 128;     // block's global row base
  const int cl = lane & 31;            // col within 32-tile / A-row within tile
  const int rquad = (lane >> 5) * 4;   // C-layout row contribution of lane-half
  const int s = (blockIdx.x >> 3) & 31;  // kk stagger: same-XCD blocks offset

  const float lam = expf(log_lam[0]);

  f32x16 acc[2][2];  // [row-tile][col-tile] within the wave's 64x64 tile.
                     // C layout: col=lane&31, row=(reg&3)+8*(reg>>2)+4*(lane>>5)

  // ---- init + epilogue0 in one pass: load u once; a_1 = soft(0.1*u) -> sA;
  // acc = C_1-pre-GEMM = 0.9*(-u) - u = -1.9u.
  #pragma unroll
  for (int rt = 0; rt < 2; ++rt) {
    #pragma unroll
    for (int ctl = 0; ctl < 2; ++ctl) {
      const int lrow = wr * 64 + rt * 32 + rquad;      // block-local row base
      const int gcol = wc * 64 + ctl * 32 + cl;
      const float* ub = u_g + (R0 + lrow) * 512 + gcol;
      unsigned short* sa = &sA[lrow * 520 + gcol];
      #pragma unroll
      for (int reg = 0; reg < 16; ++reg) {
        const int rofs = (reg & 3) + 8 * (reg >> 2);
        float uv = ub[rofs * 512];
        float v = ETA * uv;  // v_1 = 0.1*u
        float av = copysignf(fmaxf(fabsf(v) - lam, 0.f), v);
        sa[rofs * 520] = f2bf(av);
        acc[rt][ctl][reg] = -1.9f * uv;
      }
    }
  }
  __syncthreads();

  const bf16x8* gb = (const bf16x8*)Gb;
  const int bb = (wc * 2) * 64 + lane;  // B-frag base for ct = wc*2 (+64 for ct+1)
  // A-fragment: A[m][k], m = cl (local row in 32-tile), k = kko*16 + (lane>>5)*8 + j
  const unsigned short* paRow = sA + (wr * 64 + cl) * 520 + ((lane >> 5) << 3);

  #pragma unroll 1
  for (int t = 1; t < 10; ++t) {
    #pragma unroll 2
    for (int kk = 0; kk < 32; ++kk) {
      const int kko = (kk + s) & 31;
      bf16x8 b0 = gb[bb + kko * 1024];
      bf16x8 b1 = gb[bb + kko * 1024 + 64];
      bf16x8 a0 = *(const bf16x8*)(paRow + kko * 16);
      bf16x8 a1 = *(const bf16x8*)(paRow + 32 * 520 + kko * 16);
      __builtin_amdgcn_s_setprio(1);
      acc[0][0] = __builtin_amdgcn_mfma_f32_32x32x16_bf16(a0, b0, acc[0][0], 0, 0, 0);
      acc[0][1] = __builtin_amdgcn_mfma_f32_32x32x16_bf16(a0, b1, acc[0][1], 0, 0, 0);
      acc[1][0] = __builtin_amdgcn_mfma_f32_32x32x16_bf16(a1, b0, acc[1][0], 0, 0, 0);
      acc[1][1] = __builtin_amdgcn_mfma_f32_32x32x16_bf16(a1, b1, acc[1][1], 0, 0, 0);
      __builtin_amdgcn_s_setprio(0);
    }
    if (t < 9) {
      __syncthreads();  // all A-reads of this GEMM done before overwrite
      // epilogue: a_{t+1} = soft(-ETA*acc) -> sA; acc = 0.9*acc - u (u reloaded,
      // nontemporal: L3-resident, don't pollute L2 where G lives).
      #pragma unroll
      for (int rt = 0; rt < 2; ++rt) {
        #pragma unroll
        for (int ctl = 0; ctl < 2; ++ctl) {
          const int lrow = wr * 64 + rt * 32 + rquad;
          const int gcol = wc * 64 + ctl * 32 + cl;
          const float* ub = u_g + (R0 + lrow) * 512 + gcol;
          unsigned short* sa = &sA[lrow * 520 + gcol];
          #pragma unroll
          for (int reg = 0; reg < 16; ++reg) {
            const int rofs = (reg & 3) + 8 * (reg >> 2);
            float uv = __builtin_nontemporal_load(ub + rofs * 512);
            float v = -ETA * acc[rt][ctl][reg];
            float av = copysignf(fmaxf(fabsf(v) - lam, 0.f), v);
            sa[rofs * 520] = f2bf(av);
            acc[rt][ctl][reg] = 0.9f * acc[rt][ctl][reg] - uv;
          }
        }
      }
      __syncthreads();  // publish a_{t+1}
    }
  }

  // ---- final output: a_10 = soft(-ETA * acc), nontemporal (write-once)
  #pragma unroll
  for (int rt = 0; rt < 2; ++rt) {
    #pragma unroll
    for (int ctl = 0; ctl < 2; ++ctl) {
      const int lrow = wr * 64 + rt * 32 + rquad;
      const int gcol = wc * 64 + ctl * 32 + cl;
      float* ob = out + (R0 + lrow) * 512 + gcol;
      #pragma unroll
      for (int reg = 0; reg < 16; ++reg) {
        const int rofs = (reg & 3) + 8 * (reg >> 2);
        float v = -ETA * acc[rt][ctl][reg];
        float av = copysignf(fmaxf(fabsf(v) - lam, 0.f), v);
        __builtin_nontemporal_store(av, ob + rofs * 512);
      }
    }
  }
}

extern "C" void kernel_launch(void* const* d_in, const int* in_sizes, int n_in,
                              void* d_out, int out_size, void* d_ws, size_t ws_size,
                              hipStream_t stream) {
  const float* u = (const float*)d_in[0];
  const float* Graw = (const float*)d_in[1];
  const float* log_lam = (const float*)d_in[2];
  float* out = (float*)d_out;
  unsigned short* Gb = (unsigned short*)d_ws;  // 512*512*2 = 512 KB scratch

  prep_G<<<dim3(1024), dim3(256), 0, stream>>>(Graw, Gb);
  lca_kernel<<<dim3(512), dim3(1024), 0, stream>>>(u, Gb, log_lam, out);
}

// Round 4
// 708.201 us; speedup vs baseline: 1.1149x; 1.1149x over previous
//
#include <hip/hip_runtime.h>
#include <hip/hip_bf16.h>

// LCA sparsifier: 10 iterations of v = 0.9v + 0.1u - 0.1*(a@G); a = soft(v, lam)
// R4 = R3 geometry with the nontemporal hints REMOVED (R3 post-mortem: nt loads
// bypass Infinity-Cache allocation -> all 9x128MB u re-reads went to HBM,
// FETCH_SIZE 1.27GB, MfmaUtil 21%).
//  - 64x64 wave tiles, block = 128 rows x 512 cols, 16 waves; acc[2][2] = 64 AGPR
//    + 64 arch = 128 unified -> 16 waves/CU (measured Occupancy 47%).
//  - u reloaded in each epilogue via PLAIN cached loads: L3-resident after the
//    cold pass (128MB << 256MB), numerics exact.
//  - plain stores for out (nt stores inflated WRITE_SIZE 131->299MB in R3).
//  - single-buffered sA[128][520] = 133 KB, 2 barriers/iter.

typedef __attribute__((ext_vector_type(8))) short bf16x8;
typedef __attribute__((ext_vector_type(16))) float f32x16;

#define ETA 0.1f

__device__ __forceinline__ unsigned short f2bf(float f) {
  union { float f; unsigned u; } x; x.f = f;
  unsigned r = x.u + 0x7fffu + ((x.u >> 16) & 1u);  // round-to-nearest-even
  return (unsigned short)(r >> 16);
}

// ---- prep: G = 0.5(Graw + Graw^T), zero diag, bf16, swizzled into
// mfma_f32_32x32x16_bf16 B-fragment order: B[k][n], lane = (n&31) + 32*((k>>3)&1),
// j = k&7, frag index = (kk*16 + ct)*64 + lane  with kk=k>>4, ct=n>>5.
__global__ void prep_G(const float* __restrict__ Graw, unsigned short* __restrict__ Gb) {
  int idx = blockIdx.x * blockDim.x + threadIdx.x;  // 512*512 elements
  int k = idx >> 9, n = idx & 511;
  float g = 0.5f * (Graw[k * 512 + n] + Graw[n * 512 + k]);
  if (k == n) g = 0.f;
  int kk = k >> 4, ct = n >> 5;
  int lane = (n & 31) + (((k >> 3) & 1) << 5);
  int j = k & 7;
  Gb[((((kk * 16 + ct) * 64) + lane) << 3) + j] = f2bf(g);
}

__global__ __launch_bounds__(1024, 4) void lca_kernel(
    const float* __restrict__ u_g, const unsigned short* __restrict__ Gb,
    const float* __restrict__ log_lam, float* __restrict__ out) {
  // a-buffer: 128 rows x 512 cols bf16, row stride 520 (1040B = 16*65 -> the
  // 8-lane b128 phases of an A-fragment read cover all 8 bank groups; 0 conflicts).
  __shared__ unsigned short sA[128 * 520];

  const int tid = threadIdx.x;
  const int lane = tid & 63;
  const int wave = tid >> 6;           // 0..15
  const int wr = wave >> 3;            // 0..1: row group (64 rows)
  const int wc = wave & 7;             // 0..7: col group (64 cols)
  const int R0 = blockIdx.x * 128;     // block's global row base
  const int cl = lane & 31;            // col within 32-tile / A-row within tile
  const int rquad = (lane >> 5) * 4;   // C-layout row contribution of lane-half
  const int s = (blockIdx.x >> 3) & 31;  // kk stagger: same-XCD blocks offset

  const float lam = expf(log_lam[0]);

  f32x16 acc[2][2];  // [row-tile][col-tile] within the wave's 64x64 tile.
                     // C layout: col=lane&31, row=(reg&3)+8*(reg>>2)+4*(lane>>5)

  // ---- init + epilogue0 in one pass: load u once; a_1 = soft(0.1*u) -> sA;
  // acc = C_1-pre-GEMM = 0.9*(-u) - u = -1.9u.
  #pragma unroll
  for (int rt = 0; rt < 2; ++rt) {
    #pragma unroll
    for (int ctl = 0; ctl < 2; ++ctl) {
      const int lrow = wr * 64 + rt * 32 + rquad;      // block-local row base
      const int gcol = wc * 64 + ctl * 32 + cl;
      const float* ub = u_g + (R0 + lrow) * 512 + gcol;
      unsigned short* sa = &sA[lrow * 520 + gcol];
      #pragma unroll
      for (int reg = 0; reg < 16; ++reg) {
        const int rofs = (reg & 3) + 8 * (reg >> 2);
        float uv = ub[rofs * 512];
        float v = ETA * uv;  // v_1 = 0.1*u
        float av = copysignf(fmaxf(fabsf(v) - lam, 0.f), v);
        sa[rofs * 520] = f2bf(av);
        acc[rt][ctl][reg] = -1.9f * uv;
      }
    }
  }
  __syncthreads();

  const bf16x8* gb = (const bf16x8*)Gb;
  const int bb = (wc * 2) * 64 + lane;  // B-frag base for ct = wc*2 (+64 for ct+1)
  // A-fragment: A[m][k], m = cl (local row in 32-tile), k = kko*16 + (lane>>5)*8 + j
  const unsigned short* paRow = sA + (wr * 64 + cl) * 520 + ((lane >> 5) << 3);

  #pragma unroll 1
  for (int t = 1; t < 10; ++t) {
    #pragma unroll 2
    for (int kk = 0; kk < 32; ++kk) {
      const int kko = (kk + s) & 31;
      bf16x8 b0 = gb[bb + kko * 1024];
      bf16x8 b1 = gb[bb + kko * 1024 + 64];
      bf16x8 a0 = *(const bf16x8*)(paRow + kko * 16);
      bf16x8 a1 = *(const bf16x8*)(paRow + 32 * 520 + kko * 16);
      __builtin_amdgcn_s_setprio(1);
      acc[0][0] = __builtin_amdgcn_mfma_f32_32x32x16_bf16(a0, b0, acc[0][0], 0, 0, 0);
      acc[0][1] = __builtin_amdgcn_mfma_f32_32x32x16_bf16(a0, b1, acc[0][1], 0, 0, 0);
      acc[1][0] = __builtin_amdgcn_mfma_f32_32x32x16_bf16(a1, b0, acc[1][0], 0, 0, 0);
      acc[1][1] = __builtin_amdgcn_mfma_f32_32x32x16_bf16(a1, b1, acc[1][1], 0, 0, 0);
      __builtin_amdgcn_s_setprio(0);
    }
    if (t < 9) {
      __syncthreads();  // all A-reads of this GEMM done before overwrite
      // epilogue: a_{t+1} = soft(-ETA*acc) -> sA; acc = 0.9*acc - u.
      // u reloads are plain cached loads: L3-resident, 64 independent loads
      // per thread x 16 waves hide their own latency.
      #pragma unroll
      for (int rt = 0; rt < 2; ++rt) {
        #pragma unroll
        for (int ctl = 0; ctl < 2; ++ctl) {
          const int lrow = wr * 64 + rt * 32 + rquad;
          const int gcol = wc * 64 + ctl * 32 + cl;
          const float* ub = u_g + (R0 + lrow) * 512 + gcol;
          unsigned short* sa = &sA[lrow * 520 + gcol];
          #pragma unroll
          for (int reg = 0; reg < 16; ++reg) {
            const int rofs = (reg & 3) + 8 * (reg >> 2);
            float uv = ub[rofs * 512];
            float v = -ETA * acc[rt][ctl][reg];
            float av = copysignf(fmaxf(fabsf(v) - lam, 0.f), v);
            sa[rofs * 520] = f2bf(av);
            acc[rt][ctl][reg] = 0.9f * acc[rt][ctl][reg] - uv;
          }
        }
      }
      __syncthreads();  // publish a_{t+1}
    }
  }

  // ---- final output: a_10 = soft(-ETA * acc)
  #pragma unroll
  for (int rt = 0; rt < 2; ++rt) {
    #pragma unroll
    for (int ctl = 0; ctl < 2; ++ctl) {
      const int lrow = wr * 64 + rt * 32 + rquad;
      const int gcol = wc * 64 + ctl * 32 + cl;
      float* ob = out + (R0 + lrow) * 512 + gcol;
      #pragma unroll
      for (int reg = 0; reg < 16; ++reg) {
        const int rofs = (reg & 3) + 8 * (reg >> 2);
        float v = -ETA * acc[rt][ctl][reg];
        ob[rofs * 512] = copysignf(fmaxf(fabsf(v) - lam, 0.f), v);
      }
    }
  }
}

extern "C" void kernel_launch(void* const* d_in, const int* in_sizes, int n_in,
                              void* d_out, int out_size, void* d_ws, size_t ws_size,
                              hipStream_t stream) {
  const float* u = (const float*)d_in[0];
  const float* Graw = (const float*)d_in[1];
  const float* log_lam = (const float*)d_in[2];
  float* out = (float*)d_out;
  unsigned short* Gb = (unsigned short*)d_ws;  // 512*512*2 = 512 KB scratch

  prep_G<<<dim3(1024), dim3(256), 0, stream>>>(Graw, Gb);
  lca_kernel<<<dim3(512), dim3(1024), 0, stream>>>(u, Gb, log_lam, out);
}

// Round 6
// 476.616 us; speedup vs baseline: 1.6567x; 1.4859x over previous
//
#include <hip/hip_runtime.h>
#include <hip/hip_bf16.h>

// LCA sparsifier: 10 iterations of v = 0.9v + 0.1u - 0.1*(a@G); a = soft(v, lam)
// R6 = R5 resubmit (R5 bench was an infra failure: container acquire failed twice;
// no kernel verdict). Design unchanged:
// R0 geometry (64x64 wave tiles, 8-wave/512-thread blocks, uu in registers,
// 2 waves/SIMD at <=256 regs) + the latency machinery R0 was missing:
//  - depth-4 named-register B pipeline: load slab kk+4 while consuming kk
//    (prefetch distance ~4 kk-steps >> ~300cy L2 latency). Modular slab indices
//    make the pipeline SELF-PRIMING across t (G addresses repeat every iter).
//  - kk stagger s=(bid>>3)&31 spreads same-XCD blocks across G's 32 slabs.
//  - double-buffered sA (133 KB) -> ONE barrier/iter; epilogue overlaps slow
//    waves' GEMM.
//  - s_setprio(1) around the MFMA quad.
// Pipe model per CU per 64-row iter: L2-B 9.4k cyc (top), MFMA 8.3k, LDS-A 6.1k
// (halved vs R2 by the 2x2 fragment reuse), VALU ~3k. R2's 4-wave/SIMD TLP
// regime made explicit pipelining null; at 2 waves/SIMD it is load-latency-bound
// (R0: 30k cyc/iter observed vs 9.4k pipe bound) -> the regime where depth pays.

typedef __attribute__((ext_vector_type(8))) short bf16x8;
typedef __attribute__((ext_vector_type(16))) float f32x16;

#define ETA 0.1f

__device__ __forceinline__ unsigned short f2bf(float f) {
  union { float f; unsigned u; } x; x.f = f;
  unsigned r = x.u + 0x7fffu + ((x.u >> 16) & 1u);  // round-to-nearest-even
  return (unsigned short)(r >> 16);
}

// ---- prep: G = 0.5(Graw + Graw^T), zero diag, bf16, swizzled into
// mfma_f32_32x32x16_bf16 B-fragment order: B[k][n], lane = (n&31) + 32*((k>>3)&1),
// j = k&7, frag index = (kk*16 + ct)*64 + lane  with kk=k>>4, ct=n>>5.
__global__ void prep_G(const float* __restrict__ Graw, unsigned short* __restrict__ Gb) {
  int idx = blockIdx.x * blockDim.x + threadIdx.x;  // 512*512 elements
  int k = idx >> 9, n = idx & 511;
  float g = 0.5f * (Graw[k * 512 + n] + Graw[n * 512 + k]);
  if (k == n) g = 0.f;
  int kk = k >> 4, ct = n >> 5;
  int lane = (n & 31) + (((k >> 3) & 1) << 5);
  int j = k & 7;
  Gb[((((kk * 16 + ct) * 64) + lane) << 3) + j] = f2bf(g);
}

__global__ __launch_bounds__(512, 2) void lca_kernel(
    const float* __restrict__ u_g, const unsigned short* __restrict__ Gb,
    const float* __restrict__ log_lam, float* __restrict__ out) {
  // a-buffer: double-buffered 64 rows x 512 cols bf16, row stride 520
  // (1040B = 16*65 -> the 8-lane b128 phases of an A-fragment read cover all
  // 8 bank groups; measured 0 bank conflicts). 133 KB -> 1 block/CU.
  __shared__ unsigned short sA[2][64 * 520];

  const int tid = threadIdx.x;
  const int lane = tid & 63;
  const int wave = tid >> 6;           // 0..7, owns cols [wave*64, wave*64+64)
  const int R0 = blockIdx.x * 64;      // block's global row base
  const int cl = lane & 31;            // col within 32-tile / A-row within tile
  const int rquad = (lane >> 5) * 4;   // C-layout row contribution of lane-half
  const int C0 = wave * 64;
  const int s = (blockIdx.x >> 3) & 31;  // kk stagger

  const float lam = expf(log_lam[0]);

  f32x16 acc[2][2];  // wave's 64x64 tile; C layout: col=lane&31,
                     // row=(reg&3)+8*(reg>>2)+4*(lane>>5)
  f32x16 uu[2][2];   // u kept in registers across all 10 iterations (exact)

  // ---- init + epilogue0: load u once; a_1 = soft(0.1*u) -> sA[0];
  // acc = C-pre-GEMM for t=1: 0.9*(-u) - u = -1.9u.
  #pragma unroll
  for (int rt = 0; rt < 2; ++rt) {
    #pragma unroll
    for (int ctl = 0; ctl < 2; ++ctl) {
      const int lrow = rt * 32 + rquad;
      const int gcol = C0 + ctl * 32 + cl;
      const float* ub = u_g + (R0 + lrow) * 512 + gcol;
      unsigned short* sa = &sA[0][lrow * 520 + gcol];
      #pragma unroll
      for (int reg = 0; reg < 16; ++reg) {
        const int rofs = (reg & 3) + 8 * (reg >> 2);
        float uv = ub[rofs * 512];
        uu[rt][ctl][reg] = uv;
        float v = ETA * uv;  // v_1 = 0.1*u
        float av = copysignf(fmaxf(fabsf(v) - lam, 0.f), v);
        sa[rofs * 520] = f2bf(av);
        acc[rt][ctl][reg] = -1.9f * uv;
      }
    }
  }

  const bf16x8* gb = (const bf16x8*)Gb;
  const int bb = (wave * 2) * 64 + lane;  // B-frag base: ct = wave*2 (+64 -> ct+1)

  // ---- prime the depth-4 B pipeline: slots 0..3 <- slabs (s+0..3)&31.
  // Independent of sA; in flight across the barrier.
  bf16x8 p0a = gb[bb + ((s + 0) & 31) * 1024], p0b = gb[bb + ((s + 0) & 31) * 1024 + 64];
  bf16x8 p1a = gb[bb + ((s + 1) & 31) * 1024], p1b = gb[bb + ((s + 1) & 31) * 1024 + 64];
  bf16x8 p2a = gb[bb + ((s + 2) & 31) * 1024], p2b = gb[bb + ((s + 2) & 31) * 1024 + 64];
  bf16x8 p3a = gb[bb + ((s + 3) & 31) * 1024], p3b = gb[bb + ((s + 3) & 31) * 1024 + 64];

  __syncthreads();

  // epilogue: a_{t+1} = soft(-ETA*acc) -> LDS buffer; acc = 0.9*acc - u
  auto epilogue = [&](unsigned short* sbuf) {
    #pragma unroll
    for (int rt = 0; rt < 2; ++rt) {
      #pragma unroll
      for (int ctl = 0; ctl < 2; ++ctl) {
        unsigned short* sa = &sbuf[(rt * 32 + rquad) * 520 + C0 + ctl * 32 + cl];
        #pragma unroll
        for (int reg = 0; reg < 16; ++reg) {
          const int rofs = (reg & 3) + 8 * (reg >> 2);
          float v = -ETA * acc[rt][ctl][reg];
          float av = copysignf(fmaxf(fabsf(v) - lam, 0.f), v);
          sa[rofs * 520] = f2bf(av);
          acc[rt][ctl][reg] = 0.9f * acc[rt][ctl][reg] - uu[rt][ctl][reg];
        }
      }
    }
  };

  // one pipeline step: consume slot (a-reads + 4 MFMA), then reload it 4 ahead.
  // SSA form lets the compiler issue the reload before/among the MFMAs (WAR is
  // renamed away); loop-carried distance = 4 kk-steps >> L2 latency.
#define STEP(KBASE, J, PA, PB)                                                   \
  do {                                                                           \
    const int kc = ((KBASE) + (J) + s) & 31;                                     \
    const int kl = ((KBASE) + (J) + 4 + s) & 31;                                 \
    bf16x8 a0 = *(const bf16x8*)(paRow + kc * 16);                               \
    bf16x8 a1 = *(const bf16x8*)(paRow + 32 * 520 + kc * 16);                    \
    __builtin_amdgcn_s_setprio(1);                                               \
    acc[0][0] = __builtin_amdgcn_mfma_f32_32x32x16_bf16(a0, PA, acc[0][0], 0, 0, 0); \
    acc[0][1] = __builtin_amdgcn_mfma_f32_32x32x16_bf16(a0, PB, acc[0][1], 0, 0, 0); \
    acc[1][0] = __builtin_amdgcn_mfma_f32_32x32x16_bf16(a1, PA, acc[1][0], 0, 0, 0); \
    acc[1][1] = __builtin_amdgcn_mfma_f32_32x32x16_bf16(a1, PB, acc[1][1], 0, 0, 0); \
    __builtin_amdgcn_s_setprio(0);                                               \
    PA = gb[bb + kl * 1024];                                                     \
    PB = gb[bb + kl * 1024 + 64];                                                \
  } while (0)

  #pragma unroll 1
  for (int t = 1; t < 10; ++t) {
    // GEMM t reads a_t from buffer (t+1)&1.
    // A-fragment: A[m][k], m = cl (row in 32-tile), k = kc*16 + (lane>>5)*8 + j
    const unsigned short* paRow = sA[(t + 1) & 1] + cl * 520 + ((lane >> 5) << 3);
    #pragma unroll 1
    for (int grp = 0; grp < 8; ++grp) {
      const int k4 = grp * 4;
      STEP(k4, 0, p0a, p0b);
      STEP(k4, 1, p1a, p1b);
      STEP(k4, 2, p2a, p2b);
      STEP(k4, 3, p3a, p3b);
    }
    // last group's reloads hit slabs (s+0..3)&31 = next iteration's first four:
    // pipeline is self-primed across t (G constant). After t=9 they're dead.
    if (t < 9) {
      epilogue(sA[t & 1]);  // writes the OTHER buffer
      __syncthreads();      // publish a_{t+1}
    }
  }
#undef STEP

  // ---- final output: a_10 = soft(-ETA * acc)
  #pragma unroll
  for (int rt = 0; rt < 2; ++rt) {
    #pragma unroll
    for (int ctl = 0; ctl < 2; ++ctl) {
      float* ob = out + (R0 + rt * 32 + rquad) * 512 + C0 + ctl * 32 + cl;
      #pragma unroll
      for (int reg = 0; reg < 16; ++reg) {
        const int rofs = (reg & 3) + 8 * (reg >> 2);
        float v = -ETA * acc[rt][ctl][reg];
        ob[rofs * 512] = copysignf(fmaxf(fabsf(v) - lam, 0.f), v);
      }
    }
  }
}

extern "C" void kernel_launch(void* const* d_in, const int* in_sizes, int n_in,
                              void* d_out, int out_size, void* d_ws, size_t ws_size,
                              hipStream_t stream) {
  const float* u = (const float*)d_in[0];
  const float* Graw = (const float*)d_in[1];
  const float* log_lam = (const float*)d_in[2];
  float* out = (float*)d_out;
  unsigned short* Gb = (unsigned short*)d_ws;  // 512*512*2 = 512 KB scratch

  prep_G<<<dim3(1024), dim3(256), 0, stream>>>(Graw, Gb);
  lca_kernel<<<dim3(1024), dim3(512), 0, stream>>>(u, Gb, log_lam, out);
}

// Round 7
// 475.514 us; speedup vs baseline: 1.6605x; 1.0023x over previous
//
#include <hip/hip_runtime.h>
#include <hip/hip_bf16.h>

// LCA sparsifier: 10 iterations of v = 0.9v + 0.1u - 0.1*(a@G); a = soft(v, lam)
// R7: B-amortization push. R2(16w/4-SIMD) and R6(8w/2-SIMD,depth-4) both hit the
// SAME 21.9k cyc/64-row wall -> common pipe = L2 B-traffic (512KB of G per
// block-iter, invariant in rows). True shared-hot-set L2 BW ~30-40 B/cyc/CU
// (34.5TB/s ubench includes L1 reuse) -> GEMM phase is L2-bound. Only lever:
// more rows per block-iter. Register-exact max = 96 rows (acc[3][2] 96 +
// uu[3][2] 96 + ~65 working ~ 256-reg cap at 2 waves/SIMD).
//  - template<NRT>: NRT=3 (96-row) x512 blocks + NRT=2 (64-row) x256 blocks
//    = 65536 rows exactly, 3 blocks/CU, no imbalance.
//  - depth-2 named-register B pipeline (16 regs; distance ~2 kk-steps covers
//    L2 latency), kk stagger, setprio.
//  - single-buffered sA (96x520x2 = 100KB), 2 barriers/iter.
// u stays f32 in registers: exact numerics (absmax must stay 0.015625).

typedef __attribute__((ext_vector_type(8))) short bf16x8;
typedef __attribute__((ext_vector_type(16))) float f32x16;

#define ETA 0.1f

__device__ __forceinline__ unsigned short f2bf(float f) {
  union { float f; unsigned u; } x; x.f = f;
  unsigned r = x.u + 0x7fffu + ((x.u >> 16) & 1u);  // round-to-nearest-even
  return (unsigned short)(r >> 16);
}

// ---- prep: G = 0.5(Graw + Graw^T), zero diag, bf16, swizzled into
// mfma_f32_32x32x16_bf16 B-fragment order: B[k][n], lane = (n&31) + 32*((k>>3)&1),
// j = k&7, frag index = (kk*16 + ct)*64 + lane  with kk=k>>4, ct=n>>5.
__global__ void prep_G(const float* __restrict__ Graw, unsigned short* __restrict__ Gb) {
  int idx = blockIdx.x * blockDim.x + threadIdx.x;  // 512*512 elements
  int k = idx >> 9, n = idx & 511;
  float g = 0.5f * (Graw[k * 512 + n] + Graw[n * 512 + k]);
  if (k == n) g = 0.f;
  int kk = k >> 4, ct = n >> 5;
  int lane = (n & 31) + (((k >> 3) & 1) << 5);
  int j = k & 7;
  Gb[((((kk * 16 + ct) * 64) + lane) << 3) + j] = f2bf(g);
}

template <int NRT>  // rows per block = NRT*32
__global__ __launch_bounds__(512, 2) void lca_kernel(
    const float* __restrict__ u_g, const unsigned short* __restrict__ Gb,
    const float* __restrict__ log_lam, float* __restrict__ out, int row_base) {
  // a-buffer: NRT*32 rows x 512 cols bf16, row stride 520 (1040B = 16*65 ->
  // the 8-lane b128 phases of an A-fragment read cover all 8 bank groups;
  // measured 0 conflicts). NRT=3: 99,840 B.
  __shared__ unsigned short sA[NRT * 32 * 520];

  const int tid = threadIdx.x;
  const int lane = tid & 63;
  const int wave = tid >> 6;           // 0..7, owns cols [wave*64, wave*64+64)
  const int R0 = row_base + blockIdx.x * (NRT * 32);
  const int cl = lane & 31;            // col within 32-tile / A-row within tile
  const int rquad = (lane >> 5) * 4;   // C-layout row contribution of lane-half
  const int C0 = wave * 64;
  const int s = (blockIdx.x >> 3) & 31;  // kk stagger across same-XCD blocks

  const float lam = expf(log_lam[0]);

  f32x16 acc[NRT][2];  // wave tile NRT*32 rows x 64 cols; C layout:
                       // col=lane&31, row=(reg&3)+8*(reg>>2)+4*(lane>>5)
  f32x16 uu[NRT][2];   // u kept f32 in registers across all 10 iters (exact)

  // ---- init + epilogue0: load u once; a_1 = soft(0.1*u) -> sA;
  // acc = C-pre-GEMM for t=1: 0.9*(-u) - u = -1.9u.
  #pragma unroll
  for (int rt = 0; rt < NRT; ++rt) {
    #pragma unroll
    for (int ctl = 0; ctl < 2; ++ctl) {
      const int lrow = rt * 32 + rquad;
      const int gcol = C0 + ctl * 32 + cl;
      const float* ub = u_g + (R0 + lrow) * 512 + gcol;
      unsigned short* sa = &sA[lrow * 520 + gcol];
      #pragma unroll
      for (int reg = 0; reg < 16; ++reg) {
        const int rofs = (reg & 3) + 8 * (reg >> 2);
        float uv = ub[rofs * 512];
        uu[rt][ctl][reg] = uv;
        float v = ETA * uv;  // v_1 = 0.1*u
        float av = copysignf(fmaxf(fabsf(v) - lam, 0.f), v);
        sa[rofs * 520] = f2bf(av);
        acc[rt][ctl][reg] = -1.9f * uv;
      }
    }
  }

  const bf16x8* gb = (const bf16x8*)Gb;
  const int bb = (wave * 2) * 64 + lane;  // B-frag base: ct = wave*2 (+64 -> ct+1)

  // ---- prime depth-2 B pipeline: slots 0,1 <- slabs (s+0), (s+1).
  // Independent of sA; in flight across the barrier.
  bf16x8 P0a = gb[bb + ((s + 0) & 31) * 1024], P0b = gb[bb + ((s + 0) & 31) * 1024 + 64];
  bf16x8 P1a = gb[bb + ((s + 1) & 31) * 1024], P1b = gb[bb + ((s + 1) & 31) * 1024 + 64];

  __syncthreads();

  // A-fragment: A[m][k], m = cl (row in 32-tile), k = kc*16 + (lane>>5)*8 + j
  const unsigned short* paRow = sA + cl * 520 + ((lane >> 5) << 3);

  // one pipeline step: consume slot (A-reads + 2*NRT MFMA), reload it 2 ahead.
  // SSA renaming lets the reload issue among the MFMAs; loop-carried distance
  // = 2 kk-steps covers L2 latency. Wrap-around reloads at kk=30/31 hit slabs
  // s, s+1 = next t's first two -> self-priming across t (G constant).
#define STEP(KK, PA, PB)                                                         \
  do {                                                                           \
    const int kc = ((KK) + s) & 31;                                              \
    const int kl = ((KK) + 2 + s) & 31;                                          \
    bf16x8 a_[NRT];                                                              \
    _Pragma("unroll")                                                            \
    for (int rt = 0; rt < NRT; ++rt)                                             \
      a_[rt] = *(const bf16x8*)(paRow + rt * (32 * 520) + kc * 16);              \
    __builtin_amdgcn_s_setprio(1);                                               \
    _Pragma("unroll")                                                            \
    for (int rt = 0; rt < NRT; ++rt) {                                           \
      acc[rt][0] = __builtin_amdgcn_mfma_f32_32x32x16_bf16(a_[rt], PA, acc[rt][0], 0, 0, 0); \
      acc[rt][1] = __builtin_amdgcn_mfma_f32_32x32x16_bf16(a_[rt], PB, acc[rt][1], 0, 0, 0); \
    }                                                                            \
    __builtin_amdgcn_s_setprio(0);                                               \
    PA = gb[bb + kl * 1024];                                                     \
    PB = gb[bb + kl * 1024 + 64];                                                \
  } while (0)

  #pragma unroll 1
  for (int t = 1; t < 10; ++t) {
    #pragma unroll 1
    for (int kk = 0; kk < 32; kk += 2) {
      STEP(kk, P0a, P0b);
      STEP(kk + 1, P1a, P1b);
    }
    __syncthreads();  // all A-reads of this GEMM done before epilogue overwrite
    if (t < 9) {
      // epilogue: a_{t+1} = soft(-ETA*acc) -> sA; acc = 0.9*acc - u
      #pragma unroll
      for (int rt = 0; rt < NRT; ++rt) {
        #pragma unroll
        for (int ctl = 0; ctl < 2; ++ctl) {
          unsigned short* sa = &sA[(rt * 32 + rquad) * 520 + C0 + ctl * 32 + cl];
          #pragma unroll
          for (int reg = 0; reg < 16; ++reg) {
            const int rofs = (reg & 3) + 8 * (reg >> 2);
            float v = -ETA * acc[rt][ctl][reg];
            float av = copysignf(fmaxf(fabsf(v) - lam, 0.f), v);
            sa[rofs * 520] = f2bf(av);
            acc[rt][ctl][reg] = 0.9f * acc[rt][ctl][reg] - uu[rt][ctl][reg];
          }
        }
      }
      __syncthreads();  // publish a_{t+1}
    }
  }
#undef STEP

  // ---- final output: a_10 = soft(-ETA * acc)
  #pragma unroll
  for (int rt = 0; rt < NRT; ++rt) {
    #pragma unroll
    for (int ctl = 0; ctl < 2; ++ctl) {
      float* ob = out + (R0 + rt * 32 + rquad) * 512 + C0 + ctl * 32 + cl;
      #pragma unroll
      for (int reg = 0; reg < 16; ++reg) {
        const int rofs = (reg & 3) + 8 * (reg >> 2);
        float v = -ETA * acc[rt][ctl][reg];
        ob[rofs * 512] = copysignf(fmaxf(fabsf(v) - lam, 0.f), v);
      }
    }
  }
}

extern "C" void kernel_launch(void* const* d_in, const int* in_sizes, int n_in,
                              void* d_out, int out_size, void* d_ws, size_t ws_size,
                              hipStream_t stream) {
  const float* u = (const float*)d_in[0];
  const float* Graw = (const float*)d_in[1];
  const float* log_lam = (const float*)d_in[2];
  float* out = (float*)d_out;
  unsigned short* Gb = (unsigned short*)d_ws;  // 512*512*2 = 512 KB scratch

  prep_G<<<dim3(1024), dim3(256), 0, stream>>>(Graw, Gb);
  // 512 blocks x 96 rows + 256 blocks x 64 rows = 65536 rows; 3 blocks/CU total.
  lca_kernel<3><<<dim3(512), dim3(512), 0, stream>>>(u, Gb, log_lam, out, 0);
  lca_kernel<2><<<dim3(256), dim3(512), 0, stream>>>(u, Gb, log_lam, out, 512 * 96);
}